// Round 15
// baseline (19.495 us; speedup 1.0000x reference)
//
#include <hip/hip_runtime.h>
#include <stdint.h>

#define NSTEP 32
// DIM = 62 monomials of degree 1..5 over (x0,x1); collapsed to 30 gradient
// coefficients per (step, stage), PACKED as f16 pairs (lo=G0[k], hi=G1[k]).
// Both Horner chains evaluate in ONE packed v_pk_fma_f16 stream:
// inner multiplier pair xm=(x1,x0), outer xo=(x0,x1); 14 pk_fma + 2 cvt/stage.
// LDS table: sGp[step*64 + stage*15 + k] (uint32) -> 15 ds_read_b128/step/wave.
//
// STRUCTURE (R15): 2 samples/lane, 128 threads/block, 256 blocks -> 2 waves/CU.
// Halves per-CU LDS-pipe instructions (the binding constraint: was 4 waves x
// 15 reads/step x ~12cyc = 9.6us). f16 table makes the FULL-STEP double
// buffer only 120 VGPRs (R7's f32 version spilled to AGPR; R8's stage-granular
// prefetch distance was shorter than LDS latency) -> no spill, distance
// ~384cyc > ~300cyc latency, steady state VALU-bound ~5us.

typedef _Float16 h2 __attribute__((ext_vector_type(2)));

__device__ __forceinline__ h2 toh2(uint32_t w) { return __builtin_bit_cast(h2, w); }

__device__ __forceinline__ void loadstep(const uint32_t* __restrict__ sg, uint32_t (&R)[60]) {
#pragma unroll
    for (int i = 0; i < 15; ++i) {
        uint4 v = *reinterpret_cast<const uint4*>(sg + i * 4);
        R[i * 4 + 0] = v.x; R[i * 4 + 1] = v.y;
        R[i * 4 + 2] = v.z; R[i * 4 + 3] = v.w;
    }
}

template <int B>
__device__ __forceinline__ void pgrad(const uint32_t (&g)[60], h2 xm, h2 xo,
                                      float& d0, float& d1) {
    h2 r0 = toh2(g[B + 4]);
    r0 = r0 * xm + toh2(g[B + 3]);
    r0 = r0 * xm + toh2(g[B + 2]);
    r0 = r0 * xm + toh2(g[B + 1]);
    r0 = r0 * xm + toh2(g[B + 0]);
    h2 r1 = toh2(g[B + 8]);
    r1 = r1 * xm + toh2(g[B + 7]);
    r1 = r1 * xm + toh2(g[B + 6]);
    r1 = r1 * xm + toh2(g[B + 5]);
    h2 r2 = toh2(g[B + 11]);
    r2 = r2 * xm + toh2(g[B + 10]);
    r2 = r2 * xm + toh2(g[B + 9]);
    h2 r3 = toh2(g[B + 13]);
    r3 = r3 * xm + toh2(g[B + 12]);
    h2 acc = toh2(g[B + 14]);
    acc = acc * xo + r3;
    acc = acc * xo + r2;
    acc = acc * xo + r1;
    acc = acc * xo + r0;
    d0 = (float)acc.x;
    d1 = (float)acc.y;
}

__device__ __forceinline__ void mkpair(float x0, float x1, h2& xm, h2& xo) {
    xo = __builtin_bit_cast(h2, __builtin_amdgcn_cvt_pkrtz(x0, x1));   // (x0, x1)
    xm = __builtin_bit_cast(h2, __builtin_amdgcn_cvt_pkrtz(x1, x0));   // (x1, x0)
}

// one macro-step for BOTH samples; adjacent chains give 2x ILP
__device__ __forceinline__ void dostep2(const uint32_t (&g)[60],
                                        float (&q0)[2], float (&q1)[2],
                                        float (&p0)[2], float (&p1)[2],
                                        float dt, float hdt) {
    h2 xm, xo;
    float dA0[2], dA1[2];
#pragma unroll
    for (int j = 0; j < 2; ++j) {
        mkpair(p0[j], p1[j], xm, xo);
        pgrad<0>(g, xm, xo, dA0[j], dA1[j]);
        q0[j] = fmaf(dA0[j], hdt, q0[j]); q1[j] = fmaf(dA1[j], hdt, q1[j]);
    }
#pragma unroll
    for (int j = 0; j < 2; ++j) {
        mkpair(q0[j], q1[j], xm, xo);
        float dB0, dB1; pgrad<15>(g, xm, xo, dB0, dB1);
        p0[j] = fmaf(-dB0, dt, p0[j]); p1[j] = fmaf(-dB1, dt, p1[j]);
        q0[j] = fmaf(dA0[j], hdt, q0[j]); q1[j] = fmaf(dA1[j], hdt, q1[j]);
    }
    float u0[2], u1[2], v0[2], v1[2], dC0[2], dC1[2];
#pragma unroll
    for (int j = 0; j < 2; ++j) {
        u0[j] = q1[j]; u1[j] = p0[j]; v0[j] = q0[j]; v1[j] = p1[j];
        mkpair(v0[j], v1[j], xm, xo);
        pgrad<30>(g, xm, xo, dC0[j], dC1[j]);
        u0[j] = fmaf(dC1[j], hdt, u0[j]); u1[j] = fmaf(-dC0[j], hdt, u1[j]);
    }
#pragma unroll
    for (int j = 0; j < 2; ++j) {
        mkpair(u0[j], u1[j], xm, xo);
        float dD0, dD1; pgrad<45>(g, xm, xo, dD0, dD1);
        v0[j] = fmaf(dD1, dt, v0[j]); v1[j] = fmaf(-dD0, dt, v1[j]);
        u0[j] = fmaf(dC1[j], hdt, u0[j]); u1[j] = fmaf(-dC0[j], hdt, u1[j]);
        q0[j] = v0[j]; q1[j] = u0[j]; p0[j] = u1[j]; p1[j] = v1[j];
    }
}

__global__ void __launch_bounds__(128, 1)
sympl_fused(const float* __restrict__ zin,
            const float* __restrict__ Aw, const float* __restrict__ Bw,
            const float* __restrict__ Cw, const float* __restrict__ Dw,
            const int* __restrict__ nsp,
            float* __restrict__ zout, int batch) {
    __shared__ uint32_t sGp[NSTEP * 64];

    int lt = threadIdx.x;
    int base = blockIdx.x * 256;
    int i0 = base + lt, i1 = base + 128 + lt;
    bool a0 = i0 < batch, a1 = i1 < batch;

    // issue z loads first (independent of prep)
    float4 zv0 = make_float4(0.f, 0.f, 0.f, 0.f);
    float4 zv1 = make_float4(0.f, 0.f, 0.f, 0.f);
    if (a0) zv0 = reinterpret_cast<const float4*>(zin)[i0];
    if (a1) zv1 = reinterpret_cast<const float4*>(zin)[i1];
    float dt  = 1.0f / (32.0f * (float)nsp[0]);
    float hdt = 0.5f * dt;

    // ---- per-block prep: 128 (step,stage) collapse tasks, 1 per thread ----
    {
        int stepi = lt >> 2, which = lt & 3;
        const float* w;
        switch (which) { case 0: w = Aw; break; case 1: w = Bw; break;
                         case 2: w = Cw; break; default: w = Dw; }
        w += stepi * 62;                       // even offset -> 8B aligned
        const float2* w2 = reinterpret_cast<const float2*>(w);

        float c[6][6];
#pragma unroll
        for (int a = 0; a < 6; ++a)
#pragma unroll
            for (int b = 0; b < 6; ++b) c[a][b] = 0.f;
        // degree-d flat index f: bits of f = monomial indices; popcount =
        // power of x1. f even -> popc(f+1) = popc(f)+1.
#pragma unroll
        for (int d = 1; d <= 5; ++d) {
            int base2 = ((1 << d) - 2) >> 1;
#pragma unroll
            for (int fp = 0; fp < (1 << d) / 2; ++fp) {
                float2 v = w2[base2 + fp];
                int b = __popc(2 * fp);
                c[d - b][b]         += v.x;
                c[d - b - 1][b + 1] += v.y;
            }
        }

        float g0[15], g1[15];
        int k = 0;
#pragma unroll
        for (int e0 = 0; e0 <= 4; ++e0)
#pragma unroll
            for (int e1 = 0; e1 + e0 <= 4; ++e1)
                g0[k++] = (float)(e0 + 1) * c[e0 + 1][e1];
        k = 0;
#pragma unroll
        for (int e1 = 0; e1 <= 4; ++e1)
#pragma unroll
            for (int e0 = 0; e0 + e1 <= 4; ++e0)
                g1[k++] = (float)(e1 + 1) * c[e0][e1 + 1];

        uint32_t* dst = sGp + stepi * 64 + which * 15;
#pragma unroll
        for (int i = 0; i < 15; ++i) {
            h2 h; h.x = (_Float16)g0[i]; h.y = (_Float16)g1[i];
            dst[i] = __builtin_bit_cast(uint32_t, h);
        }
        if (which == 0) { sGp[stepi * 64 + 60] = 0u; sGp[stepi * 64 + 61] = 0u;
                          sGp[stepi * 64 + 62] = 0u; sGp[stepi * 64 + 63] = 0u; }
    }
    __syncthreads();

    float q0[2] = {zv0.x, zv1.x}, q1[2] = {zv0.y, zv1.y};
    float p0[2] = {zv0.z, zv1.z}, p1[2] = {zv0.w, zv1.w};

    // ---- main loop: full-step register double buffer, unroll x2 ----
    uint32_t bufX[60], bufY[60];
    loadstep(sGp, bufX);                      // step 0

#pragma unroll 1
    for (int it = 0; it < NSTEP / 2; ++it) {
        int s = 2 * it;
        loadstep(sGp + (s + 1) * 64, bufY);
        dostep2(bufX, q0, q1, p0, p1, dt, hdt);
        int sn = (s + 2 < NSTEP) ? s + 2 : NSTEP - 1;
        loadstep(sGp + sn * 64, bufX);
        dostep2(bufY, q0, q1, p0, p1, dt, hdt);
    }

    if (a0) {
        float4 o; o.x = q0[0]; o.y = q1[0]; o.z = p0[0]; o.w = p1[0];
        reinterpret_cast<float4*>(zout)[i0] = o;
    }
    if (a1) {
        float4 o; o.x = q0[1]; o.y = q1[1]; o.z = p0[1]; o.w = p1[1];
        reinterpret_cast<float4*>(zout)[i1] = o;
    }
}

extern "C" void kernel_launch(void* const* d_in, const int* in_sizes, int n_in,
                              void* d_out, int out_size, void* d_ws, size_t ws_size,
                              hipStream_t stream) {
    const float* z  = (const float*)d_in[0];
    const float* Aw = (const float*)d_in[1];
    const float* Bw = (const float*)d_in[2];
    const float* Cw = (const float*)d_in[3];
    const float* Dw = (const float*)d_in[4];
    const int*   ns = (const int*)d_in[5];

    int batch = in_sizes[0] / 4;
    int blocks = (batch + 255) / 256;   // 128 threads, 2 samples/thread
    sympl_fused<<<blocks, 128, 0, stream>>>(z, Aw, Bw, Cw, Dw, ns,
                                            (float*)d_out, batch);
}

// Round 16
// 19.484 us; speedup vs baseline: 1.0006x; 1.0006x over previous
//
#include <hip/hip_runtime.h>
#include <stdint.h>

#define NSTEP 32
// DIM = 62 monomials of degree 1..5 over (x0,x1); collapsed to 30 gradient
// coefficients per (step, stage), PACKED as f16 pairs (lo=G0[k], hi=G1[k]).
// Both Horner chains evaluate in ONE packed v_pk_fma_f16 stream:
// inner multiplier pair xm=(x1,x0), outer xo=(x0,x1); 14 pk_fma + 2 cvt/stage.
// LDS table: sGp[step*64 + stage*15 + k] (uint32) -> 15 ds_read_b128/step/wave.
//
// STRUCTURE (R15): 2 samples/lane, 128 threads/block, 256 blocks -> 2 waves/CU.
// Halves per-CU LDS-pipe instructions (the binding constraint: was 4 waves x
// 15 reads/step x ~12cyc = 9.6us). f16 table makes the FULL-STEP double
// buffer only 120 VGPRs (R7's f32 version spilled to AGPR; R8's stage-granular
// prefetch distance was shorter than LDS latency) -> no spill, distance
// ~384cyc > ~300cyc latency, steady state VALU-bound ~5us.

typedef _Float16 h2 __attribute__((ext_vector_type(2)));

__device__ __forceinline__ h2 toh2(uint32_t w) { return __builtin_bit_cast(h2, w); }

__device__ __forceinline__ void loadstep(const uint32_t* __restrict__ sg, uint32_t (&R)[60]) {
#pragma unroll
    for (int i = 0; i < 15; ++i) {
        uint4 v = *reinterpret_cast<const uint4*>(sg + i * 4);
        R[i * 4 + 0] = v.x; R[i * 4 + 1] = v.y;
        R[i * 4 + 2] = v.z; R[i * 4 + 3] = v.w;
    }
}

template <int B>
__device__ __forceinline__ void pgrad(const uint32_t (&g)[60], h2 xm, h2 xo,
                                      float& d0, float& d1) {
    h2 r0 = toh2(g[B + 4]);
    r0 = r0 * xm + toh2(g[B + 3]);
    r0 = r0 * xm + toh2(g[B + 2]);
    r0 = r0 * xm + toh2(g[B + 1]);
    r0 = r0 * xm + toh2(g[B + 0]);
    h2 r1 = toh2(g[B + 8]);
    r1 = r1 * xm + toh2(g[B + 7]);
    r1 = r1 * xm + toh2(g[B + 6]);
    r1 = r1 * xm + toh2(g[B + 5]);
    h2 r2 = toh2(g[B + 11]);
    r2 = r2 * xm + toh2(g[B + 10]);
    r2 = r2 * xm + toh2(g[B + 9]);
    h2 r3 = toh2(g[B + 13]);
    r3 = r3 * xm + toh2(g[B + 12]);
    h2 acc = toh2(g[B + 14]);
    acc = acc * xo + r3;
    acc = acc * xo + r2;
    acc = acc * xo + r1;
    acc = acc * xo + r0;
    d0 = (float)acc.x;
    d1 = (float)acc.y;
}

__device__ __forceinline__ void mkpair(float x0, float x1, h2& xm, h2& xo) {
    xo = __builtin_bit_cast(h2, __builtin_amdgcn_cvt_pkrtz(x0, x1));   // (x0, x1)
    xm = __builtin_bit_cast(h2, __builtin_amdgcn_cvt_pkrtz(x1, x0));   // (x1, x0)
}

// one macro-step for BOTH samples; adjacent chains give 2x ILP
__device__ __forceinline__ void dostep2(const uint32_t (&g)[60],
                                        float (&q0)[2], float (&q1)[2],
                                        float (&p0)[2], float (&p1)[2],
                                        float dt, float hdt) {
    h2 xm, xo;
    float dA0[2], dA1[2];
#pragma unroll
    for (int j = 0; j < 2; ++j) {
        mkpair(p0[j], p1[j], xm, xo);
        pgrad<0>(g, xm, xo, dA0[j], dA1[j]);
        q0[j] = fmaf(dA0[j], hdt, q0[j]); q1[j] = fmaf(dA1[j], hdt, q1[j]);
    }
#pragma unroll
    for (int j = 0; j < 2; ++j) {
        mkpair(q0[j], q1[j], xm, xo);
        float dB0, dB1; pgrad<15>(g, xm, xo, dB0, dB1);
        p0[j] = fmaf(-dB0, dt, p0[j]); p1[j] = fmaf(-dB1, dt, p1[j]);
        q0[j] = fmaf(dA0[j], hdt, q0[j]); q1[j] = fmaf(dA1[j], hdt, q1[j]);
    }
    float u0[2], u1[2], v0[2], v1[2], dC0[2], dC1[2];
#pragma unroll
    for (int j = 0; j < 2; ++j) {
        u0[j] = q1[j]; u1[j] = p0[j]; v0[j] = q0[j]; v1[j] = p1[j];
        mkpair(v0[j], v1[j], xm, xo);
        pgrad<30>(g, xm, xo, dC0[j], dC1[j]);
        u0[j] = fmaf(dC1[j], hdt, u0[j]); u1[j] = fmaf(-dC0[j], hdt, u1[j]);
    }
#pragma unroll
    for (int j = 0; j < 2; ++j) {
        mkpair(u0[j], u1[j], xm, xo);
        float dD0, dD1; pgrad<45>(g, xm, xo, dD0, dD1);
        v0[j] = fmaf(dD1, dt, v0[j]); v1[j] = fmaf(-dD0, dt, v1[j]);
        u0[j] = fmaf(dC1[j], hdt, u0[j]); u1[j] = fmaf(-dC0[j], hdt, u1[j]);
        q0[j] = v0[j]; q1[j] = u0[j]; p0[j] = u1[j]; p1[j] = v1[j];
    }
}

__global__ void __launch_bounds__(128, 1)
sympl_fused(const float* __restrict__ zin,
            const float* __restrict__ Aw, const float* __restrict__ Bw,
            const float* __restrict__ Cw, const float* __restrict__ Dw,
            const int* __restrict__ nsp,
            float* __restrict__ zout, int batch) {
    __shared__ uint32_t sGp[NSTEP * 64];

    int lt = threadIdx.x;
    int base = blockIdx.x * 256;
    int i0 = base + lt, i1 = base + 128 + lt;
    bool a0 = i0 < batch, a1 = i1 < batch;

    // issue z loads first (independent of prep)
    float4 zv0 = make_float4(0.f, 0.f, 0.f, 0.f);
    float4 zv1 = make_float4(0.f, 0.f, 0.f, 0.f);
    if (a0) zv0 = reinterpret_cast<const float4*>(zin)[i0];
    if (a1) zv1 = reinterpret_cast<const float4*>(zin)[i1];
    float dt  = 1.0f / (32.0f * (float)nsp[0]);
    float hdt = 0.5f * dt;

    // ---- per-block prep: 128 (step,stage) collapse tasks, 1 per thread ----
    {
        int stepi = lt >> 2, which = lt & 3;
        const float* w;
        switch (which) { case 0: w = Aw; break; case 1: w = Bw; break;
                         case 2: w = Cw; break; default: w = Dw; }
        w += stepi * 62;                       // even offset -> 8B aligned
        const float2* w2 = reinterpret_cast<const float2*>(w);

        float c[6][6];
#pragma unroll
        for (int a = 0; a < 6; ++a)
#pragma unroll
            for (int b = 0; b < 6; ++b) c[a][b] = 0.f;
        // degree-d flat index f: bits of f = monomial indices; popcount =
        // power of x1. f even -> popc(f+1) = popc(f)+1.
#pragma unroll
        for (int d = 1; d <= 5; ++d) {
            int base2 = ((1 << d) - 2) >> 1;
#pragma unroll
            for (int fp = 0; fp < (1 << d) / 2; ++fp) {
                float2 v = w2[base2 + fp];
                int b = __popc(2 * fp);
                c[d - b][b]         += v.x;
                c[d - b - 1][b + 1] += v.y;
            }
        }

        float g0[15], g1[15];
        int k = 0;
#pragma unroll
        for (int e0 = 0; e0 <= 4; ++e0)
#pragma unroll
            for (int e1 = 0; e1 + e0 <= 4; ++e1)
                g0[k++] = (float)(e0 + 1) * c[e0 + 1][e1];
        k = 0;
#pragma unroll
        for (int e1 = 0; e1 <= 4; ++e1)
#pragma unroll
            for (int e0 = 0; e0 + e1 <= 4; ++e0)
                g1[k++] = (float)(e1 + 1) * c[e0][e1 + 1];

        uint32_t* dst = sGp + stepi * 64 + which * 15;
#pragma unroll
        for (int i = 0; i < 15; ++i) {
            h2 h; h.x = (_Float16)g0[i]; h.y = (_Float16)g1[i];
            dst[i] = __builtin_bit_cast(uint32_t, h);
        }
        if (which == 0) { sGp[stepi * 64 + 60] = 0u; sGp[stepi * 64 + 61] = 0u;
                          sGp[stepi * 64 + 62] = 0u; sGp[stepi * 64 + 63] = 0u; }
    }
    __syncthreads();

    float q0[2] = {zv0.x, zv1.x}, q1[2] = {zv0.y, zv1.y};
    float p0[2] = {zv0.z, zv1.z}, p1[2] = {zv0.w, zv1.w};

    // ---- main loop: full-step register double buffer, unroll x2 ----
    uint32_t bufX[60], bufY[60];
    loadstep(sGp, bufX);                      // step 0

#pragma unroll 1
    for (int it = 0; it < NSTEP / 2; ++it) {
        int s = 2 * it;
        loadstep(sGp + (s + 1) * 64, bufY);
        dostep2(bufX, q0, q1, p0, p1, dt, hdt);
        int sn = (s + 2 < NSTEP) ? s + 2 : NSTEP - 1;
        loadstep(sGp + sn * 64, bufX);
        dostep2(bufY, q0, q1, p0, p1, dt, hdt);
    }

    if (a0) {
        float4 o; o.x = q0[0]; o.y = q1[0]; o.z = p0[0]; o.w = p1[0];
        reinterpret_cast<float4*>(zout)[i0] = o;
    }
    if (a1) {
        float4 o; o.x = q0[1]; o.y = q1[1]; o.z = p0[1]; o.w = p1[1];
        reinterpret_cast<float4*>(zout)[i1] = o;
    }
}

extern "C" void kernel_launch(void* const* d_in, const int* in_sizes, int n_in,
                              void* d_out, int out_size, void* d_ws, size_t ws_size,
                              hipStream_t stream) {
    const float* z  = (const float*)d_in[0];
    const float* Aw = (const float*)d_in[1];
    const float* Bw = (const float*)d_in[2];
    const float* Cw = (const float*)d_in[3];
    const float* Dw = (const float*)d_in[4];
    const int*   ns = (const int*)d_in[5];

    int batch = in_sizes[0] / 4;
    int blocks = (batch + 255) / 256;   // 128 threads, 2 samples/thread
    sympl_fused<<<blocks, 128, 0, stream>>>(z, Aw, Bw, Cw, Dw, ns,
                                            (float*)d_out, batch);
}

// Round 17
// 15.858 us; speedup vs baseline: 1.2293x; 1.2286x over previous
//
#include <hip/hip_runtime.h>
#include <stdint.h>

#define NSTEP 32
// DIM = 62 monomials of degree 1..5 over (x0,x1); collapsed to 30 gradient
// coefficients per (step, stage), PACKED as f16 pairs:
//   word k (k=0..14) = ( G0[k] , G1[k] ) = (lo,hi), where
//   G0 = dP/dx0 chain (triangular rows by e0, widths 5,4,3,2,1; inner Horner in x1)
//   G1 = dP/dx1 chain (rows by e1; inner Horner in x0) — index-symmetric to G0.
// Both chains evaluate in ONE packed v_pk_fma_f16 stream: inner multiplier
// pair xm=(x1,x0), outer xo=(x0,x1); 14 pk_fma + 1 cvt_pkrtz + 1 alignbit +
// 2 cvt-to-f32 per stage.
// LDS table: sGp[step*64 + stage*15 + k] (uint32) -> 15 ds_read_b128/step/wave.
// Structure = R14 (4 waves/CU, 1 sample/lane, full-step reg double buffer):
// every tested deviation (readlane R4, s_load R11, LDS-staged prep R13,
// 2-sample R7/R8/R16) regressed.

typedef _Float16 h2 __attribute__((ext_vector_type(2)));

__device__ __forceinline__ h2 toh2(uint32_t w) { return __builtin_bit_cast(h2, w); }

__device__ __forceinline__ void loadstep(const uint32_t* __restrict__ sg, uint32_t (&R)[60]) {
#pragma unroll
    for (int i = 0; i < 15; ++i) {
        uint4 v = *reinterpret_cast<const uint4*>(sg + i * 4);
        R[i * 4 + 0] = v.x; R[i * 4 + 1] = v.y;
        R[i * 4 + 2] = v.z; R[i * 4 + 3] = v.w;
    }
}

template <int B>
__device__ __forceinline__ void pgrad(const uint32_t (&g)[60], h2 xm, h2 xo,
                                      float& d0, float& d1) {
    h2 r0 = toh2(g[B + 4]);
    r0 = r0 * xm + toh2(g[B + 3]);
    r0 = r0 * xm + toh2(g[B + 2]);
    r0 = r0 * xm + toh2(g[B + 1]);
    r0 = r0 * xm + toh2(g[B + 0]);
    h2 r1 = toh2(g[B + 8]);
    r1 = r1 * xm + toh2(g[B + 7]);
    r1 = r1 * xm + toh2(g[B + 6]);
    r1 = r1 * xm + toh2(g[B + 5]);
    h2 r2 = toh2(g[B + 11]);
    r2 = r2 * xm + toh2(g[B + 10]);
    r2 = r2 * xm + toh2(g[B + 9]);
    h2 r3 = toh2(g[B + 13]);
    r3 = r3 * xm + toh2(g[B + 12]);
    h2 acc = toh2(g[B + 14]);
    acc = acc * xo + r3;
    acc = acc * xo + r2;
    acc = acc * xo + r1;
    acc = acc * xo + r0;
    d0 = (float)acc.x;
    d1 = (float)acc.y;
}

// xo = pkrtz(x0,x1); xm = halves-swapped xo (v_alignbit_b32, 1 op)
__device__ __forceinline__ void mkpair(float x0, float x1, h2& xm, h2& xo) {
    uint32_t o = __builtin_bit_cast(uint32_t, __builtin_amdgcn_cvt_pkrtz(x0, x1));
    uint32_t m = __builtin_amdgcn_alignbit(o, o, 16);
    xo = __builtin_bit_cast(h2, o);
    xm = __builtin_bit_cast(h2, m);
}

__device__ __forceinline__ void dostep(const uint32_t (&g)[60], float& q0, float& q1,
                                       float& p0, float& p1, float dt, float hdt) {
    h2 xm, xo;

    mkpair(p0, p1, xm, xo);
    float dA0, dA1; pgrad<0>(g, xm, xo, dA0, dA1);
    q0 = fmaf(dA0, hdt, q0); q1 = fmaf(dA1, hdt, q1);

    mkpair(q0, q1, xm, xo);
    float dB0, dB1; pgrad<15>(g, xm, xo, dB0, dB1);
    p0 = fmaf(-dB0, dt, p0); p1 = fmaf(-dB1, dt, p1);
    q0 = fmaf(dA0, hdt, q0); q1 = fmaf(dA1, hdt, q1);

    float u0 = q1, u1 = p0, v0 = q0, v1 = p1;

    mkpair(v0, v1, xm, xo);
    float dC0, dC1; pgrad<30>(g, xm, xo, dC0, dC1);
    u0 = fmaf(dC1, hdt, u0); u1 = fmaf(-dC0, hdt, u1);

    mkpair(u0, u1, xm, xo);
    float dD0, dD1; pgrad<45>(g, xm, xo, dD0, dD1);
    v0 = fmaf(dD1, dt, v0); v1 = fmaf(-dD0, dt, v1);
    u0 = fmaf(dC1, hdt, u0); u1 = fmaf(-dC0, hdt, u1);

    q0 = v0; q1 = u0; p0 = u1; p1 = v1;   // z = [v0, u0, u1, v1]
}

__global__ void __launch_bounds__(256, 1)
sympl_fused(const float* __restrict__ zin,
            const float* __restrict__ Aw, const float* __restrict__ Bw,
            const float* __restrict__ Cw, const float* __restrict__ Dw,
            const int* __restrict__ nsp,
            float* __restrict__ zout, int batch) {
    __shared__ uint32_t sGp[NSTEP * 64];

    int lt = threadIdx.x;
    int idx = blockIdx.x * 256 + lt;
    bool active = idx < batch;

    // issue the z load immediately (independent of prep)
    float4 zv = make_float4(0.f, 0.f, 0.f, 0.f);
    if (active) zv = reinterpret_cast<const float4*>(zin)[idx];
    float dt  = 1.0f / (32.0f * (float)nsp[0]);
    float hdt = 0.5f * dt;

    // ---- per-block redundant prep: 128 (step, stage) collapse tasks ----
    if (lt < NSTEP * 4) {
        int stepi = lt >> 2, which = lt & 3;
        const float* w;
        switch (which) { case 0: w = Aw; break; case 1: w = Bw; break;
                         case 2: w = Cw; break; default: w = Dw; }
        w += stepi * 62;                       // even offset -> 8B aligned
        const float2* w2 = reinterpret_cast<const float2*>(w);

        float c[6][6];
#pragma unroll
        for (int a = 0; a < 6; ++a)
#pragma unroll
            for (int b = 0; b < 6; ++b) c[a][b] = 0.f;
        // degree-d flat index f: bits of f = monomial indices; popcount =
        // power of x1. f even -> popc(f+1) = popc(f)+1.
#pragma unroll
        for (int d = 1; d <= 5; ++d) {
            int base2 = ((1 << d) - 2) >> 1;
#pragma unroll
            for (int fp = 0; fp < (1 << d) / 2; ++fp) {
                float2 v = w2[base2 + fp];
                int b = __popc(2 * fp);
                c[d - b][b]         += v.x;
                c[d - b - 1][b + 1] += v.y;
            }
        }

        float g0[15], g1[15];
        int k = 0;
#pragma unroll
        for (int e0 = 0; e0 <= 4; ++e0)
#pragma unroll
            for (int e1 = 0; e1 + e0 <= 4; ++e1)
                g0[k++] = (float)(e0 + 1) * c[e0 + 1][e1];
        k = 0;
#pragma unroll
        for (int e1 = 0; e1 <= 4; ++e1)
#pragma unroll
            for (int e0 = 0; e0 + e1 <= 4; ++e0)
                g1[k++] = (float)(e1 + 1) * c[e0][e1 + 1];

        uint32_t* dst = sGp + stepi * 64 + which * 15;
#pragma unroll
        for (int i = 0; i < 15; ++i) {
            h2 h; h.x = (_Float16)g0[i]; h.y = (_Float16)g1[i];
            dst[i] = __builtin_bit_cast(uint32_t, h);
        }
        if (which == 0) { sGp[stepi * 64 + 60] = 0u; sGp[stepi * 64 + 61] = 0u;
                          sGp[stepi * 64 + 62] = 0u; sGp[stepi * 64 + 63] = 0u; }
    }
    __syncthreads();

    float q0 = zv.x, q1 = zv.y, p0 = zv.z, p1 = zv.w;

    // ---- main loop: full-step register double buffer, unroll x2 ----
    uint32_t bufX[60], bufY[60];
    loadstep(sGp, bufX);                      // step 0

#pragma unroll 1
    for (int it = 0; it < NSTEP / 2; ++it) {
        int s = 2 * it;
        loadstep(sGp + (s + 1) * 64, bufY);
        dostep(bufX, q0, q1, p0, p1, dt, hdt);
        int sn = (s + 2 < NSTEP) ? s + 2 : NSTEP - 1;
        loadstep(sGp + sn * 64, bufX);
        dostep(bufY, q0, q1, p0, p1, dt, hdt);
    }

    if (active) {
        float4 o; o.x = q0; o.y = q1; o.z = p0; o.w = p1;
        reinterpret_cast<float4*>(zout)[idx] = o;
    }
}

extern "C" void kernel_launch(void* const* d_in, const int* in_sizes, int n_in,
                              void* d_out, int out_size, void* d_ws, size_t ws_size,
                              hipStream_t stream) {
    const float* z  = (const float*)d_in[0];
    const float* Aw = (const float*)d_in[1];
    const float* Bw = (const float*)d_in[2];
    const float* Cw = (const float*)d_in[3];
    const float* Dw = (const float*)d_in[4];
    const int*   ns = (const int*)d_in[5];

    int batch = in_sizes[0] / 4;
    int threads = 256;
    int blocks = (batch + threads - 1) / threads;
    sympl_fused<<<blocks, threads, 0, stream>>>(z, Aw, Bw, Cw, Dw, ns,
                                                (float*)d_out, batch);
}

// Round 18
// 15.446 us; speedup vs baseline: 1.2621x; 1.0267x over previous
//
#include <hip/hip_runtime.h>
#include <stdint.h>

#define NSTEP 32
// DIM = 62 monomials of degree 1..5 over (x0,x1); collapsed to 30 gradient
// coefficients per (step, stage), PACKED as f16 pairs:
//   word k (k=0..14) = ( G0[k] , G1[k] ) = (lo,hi), where
//   G0 = dP/dx0 chain (triangular rows by e0, widths 5,4,3,2,1; inner Horner in x1)
//   G1 = dP/dx1 chain (rows by e1; inner Horner in x0) — index-symmetric to G0.
// BOTH chains evaluate in ONE packed v_pk_fma_f16 stream: inner multiplier
// pair xm=(x1,x0), outer xo=(x0,x1); 14 pk_fma + 2 cvt_pkrtz + 2 cvt/stage.
// LDS table: sGp[step*64 + stage*15 + k] (uint32) -> 15 ds_read_b128/step/wave.
// PREP: direct-from-global float2 loads (rows 8B-aligned; every degree block
// starts at an even offset) — LDS staging (R13) and kernel-split (R10) both
// measured slower.
// Structure = measured optimum (R14, 15.46us). Falsified alternatives:
// readlane R4, uniform/const-AS loads R5/R6, s_load R11, LDS-staged prep R13,
// 2-sample R7/R8/R16, alignbit mkpair R17.

typedef _Float16 h2 __attribute__((ext_vector_type(2)));

__device__ __forceinline__ h2 toh2(uint32_t w) { return __builtin_bit_cast(h2, w); }

__device__ __forceinline__ void loadstep(const uint32_t* __restrict__ sg, uint32_t (&R)[60]) {
#pragma unroll
    for (int i = 0; i < 15; ++i) {
        uint4 v = *reinterpret_cast<const uint4*>(sg + i * 4);
        R[i * 4 + 0] = v.x; R[i * 4 + 1] = v.y;
        R[i * 4 + 2] = v.z; R[i * 4 + 3] = v.w;
    }
}

// packed dual-Horner: d0 over (inner x1, outer x0) in lo; d1 over (inner x0,
// outer x1) in hi. 14 pk_fma (mul+add contracted) + 2 cvt.
template <int B>
__device__ __forceinline__ void pgrad(const uint32_t (&g)[60], h2 xm, h2 xo,
                                      float& d0, float& d1) {
    h2 r0 = toh2(g[B + 4]);
    r0 = r0 * xm + toh2(g[B + 3]);
    r0 = r0 * xm + toh2(g[B + 2]);
    r0 = r0 * xm + toh2(g[B + 1]);
    r0 = r0 * xm + toh2(g[B + 0]);
    h2 r1 = toh2(g[B + 8]);
    r1 = r1 * xm + toh2(g[B + 7]);
    r1 = r1 * xm + toh2(g[B + 6]);
    r1 = r1 * xm + toh2(g[B + 5]);
    h2 r2 = toh2(g[B + 11]);
    r2 = r2 * xm + toh2(g[B + 10]);
    r2 = r2 * xm + toh2(g[B + 9]);
    h2 r3 = toh2(g[B + 13]);
    r3 = r3 * xm + toh2(g[B + 12]);
    h2 acc = toh2(g[B + 14]);
    acc = acc * xo + r3;
    acc = acc * xo + r2;
    acc = acc * xo + r1;
    acc = acc * xo + r0;
    d0 = (float)acc.x;
    d1 = (float)acc.y;
}

// 2 independent ops: v_cvt_pkrtz_f16_f32 packs (lo,hi) directly
__device__ __forceinline__ void mkpair(float x0, float x1, h2& xm, h2& xo) {
    xo = __builtin_bit_cast(h2, __builtin_amdgcn_cvt_pkrtz(x0, x1));   // (x0, x1)
    xm = __builtin_bit_cast(h2, __builtin_amdgcn_cvt_pkrtz(x1, x0));   // (x1, x0)
}

__device__ __forceinline__ void dostep(const uint32_t (&g)[60], float& q0, float& q1,
                                       float& p0, float& p1, float dt, float hdt) {
    h2 xm, xo;

    mkpair(p0, p1, xm, xo);
    float dA0, dA1; pgrad<0>(g, xm, xo, dA0, dA1);
    q0 = fmaf(dA0, hdt, q0); q1 = fmaf(dA1, hdt, q1);

    mkpair(q0, q1, xm, xo);
    float dB0, dB1; pgrad<15>(g, xm, xo, dB0, dB1);
    p0 = fmaf(-dB0, dt, p0); p1 = fmaf(-dB1, dt, p1);
    q0 = fmaf(dA0, hdt, q0); q1 = fmaf(dA1, hdt, q1);

    float u0 = q1, u1 = p0, v0 = q0, v1 = p1;

    mkpair(v0, v1, xm, xo);
    float dC0, dC1; pgrad<30>(g, xm, xo, dC0, dC1);
    u0 = fmaf(dC1, hdt, u0); u1 = fmaf(-dC0, hdt, u1);

    mkpair(u0, u1, xm, xo);
    float dD0, dD1; pgrad<45>(g, xm, xo, dD0, dD1);
    v0 = fmaf(dD1, dt, v0); v1 = fmaf(-dD0, dt, v1);
    u0 = fmaf(dC1, hdt, u0); u1 = fmaf(-dC0, hdt, u1);

    q0 = v0; q1 = u0; p0 = u1; p1 = v1;   // z = [v0, u0, u1, v1]
}

__global__ void __launch_bounds__(256, 1)
sympl_fused(const float* __restrict__ zin,
            const float* __restrict__ Aw, const float* __restrict__ Bw,
            const float* __restrict__ Cw, const float* __restrict__ Dw,
            const int* __restrict__ nsp,
            float* __restrict__ zout, int batch) {
    __shared__ uint32_t sGp[NSTEP * 64];

    int lt = threadIdx.x;
    int idx = blockIdx.x * 256 + lt;
    bool active = idx < batch;

    // issue the z load immediately (independent of prep)
    float4 zv = make_float4(0.f, 0.f, 0.f, 0.f);
    if (active) zv = reinterpret_cast<const float4*>(zin)[idx];
    float dt  = 1.0f / (32.0f * (float)nsp[0]);
    float hdt = 0.5f * dt;

    // ---- per-block redundant prep: 128 (step, stage) collapse tasks ----
    if (lt < NSTEP * 4) {
        int stepi = lt >> 2, which = lt & 3;
        const float* w;
        switch (which) { case 0: w = Aw; break; case 1: w = Bw; break;
                         case 2: w = Cw; break; default: w = Dw; }
        w += stepi * 62;                       // even offset -> 8B aligned
        const float2* w2 = reinterpret_cast<const float2*>(w);

        float c[6][6];
#pragma unroll
        for (int a = 0; a < 6; ++a)
#pragma unroll
            for (int b = 0; b < 6; ++b) c[a][b] = 0.f;
        // degree-d flat index f: bits of f = monomial indices; popcount =
        // power of x1. f even -> popc(f+1) = popc(f)+1.
#pragma unroll
        for (int d = 1; d <= 5; ++d) {
            int base2 = ((1 << d) - 2) >> 1;
#pragma unroll
            for (int fp = 0; fp < (1 << d) / 2; ++fp) {
                float2 v = w2[base2 + fp];
                int b = __popc(2 * fp);
                c[d - b][b]         += v.x;
                c[d - b - 1][b + 1] += v.y;
            }
        }

        float g0[15], g1[15];
        int k = 0;
#pragma unroll
        for (int e0 = 0; e0 <= 4; ++e0)
#pragma unroll
            for (int e1 = 0; e1 + e0 <= 4; ++e1)
                g0[k++] = (float)(e0 + 1) * c[e0 + 1][e1];
        k = 0;
#pragma unroll
        for (int e1 = 0; e1 <= 4; ++e1)
#pragma unroll
            for (int e0 = 0; e0 + e1 <= 4; ++e0)
                g1[k++] = (float)(e1 + 1) * c[e0][e1 + 1];

        uint32_t* dst = sGp + stepi * 64 + which * 15;
#pragma unroll
        for (int i = 0; i < 15; ++i) {
            h2 h; h.x = (_Float16)g0[i]; h.y = (_Float16)g1[i];
            dst[i] = __builtin_bit_cast(uint32_t, h);
        }
        if (which == 0) { sGp[stepi * 64 + 60] = 0u; sGp[stepi * 64 + 61] = 0u;
                          sGp[stepi * 64 + 62] = 0u; sGp[stepi * 64 + 63] = 0u; }
    }
    __syncthreads();

    float q0 = zv.x, q1 = zv.y, p0 = zv.z, p1 = zv.w;

    // ---- main loop: full-step register double buffer, unroll x2 ----
    uint32_t bufX[60], bufY[60];
    loadstep(sGp, bufX);                      // step 0

#pragma unroll 1
    for (int it = 0; it < NSTEP / 2; ++it) {
        int s = 2 * it;
        loadstep(sGp + (s + 1) * 64, bufY);
        dostep(bufX, q0, q1, p0, p1, dt, hdt);
        int sn = (s + 2 < NSTEP) ? s + 2 : NSTEP - 1;
        loadstep(sGp + sn * 64, bufX);
        dostep(bufY, q0, q1, p0, p1, dt, hdt);
    }

    if (active) {
        float4 o; o.x = q0; o.y = q1; o.z = p0; o.w = p1;
        reinterpret_cast<float4*>(zout)[idx] = o;
    }
}

extern "C" void kernel_launch(void* const* d_in, const int* in_sizes, int n_in,
                              void* d_out, int out_size, void* d_ws, size_t ws_size,
                              hipStream_t stream) {
    const float* z  = (const float*)d_in[0];
    const float* Aw = (const float*)d_in[1];
    const float* Bw = (const float*)d_in[2];
    const float* Cw = (const float*)d_in[3];
    const float* Dw = (const float*)d_in[4];
    const int*   ns = (const int*)d_in[5];

    int batch = in_sizes[0] / 4;
    int threads = 256;
    int blocks = (batch + threads - 1) / threads;
    sympl_fused<<<blocks, threads, 0, stream>>>(z, Aw, Bw, Cw, Dw, ns,
                                                (float*)d_out, batch);
}